// Round 1
// baseline (223.896 us; speedup 1.0000x reference)
//
#include <hip/hip_runtime.h>
#include <math.h>

#define BB 16
#define CC 3
#define HH 512
#define WW 512
#define HW (HH*WW)            // 262144
#define NPIX (BB*HW)          // 4194304
#define TOTAL ((double)(BB*CC*HW))  // 12582912

// ws layout (bytes):
//   [0)                : float rsr[NPIX]  (sign bit = mask r_sr < r_ema)   16,777,216 B
//   [16777216)         : double partial_s[4096]                                32,768 B
//   [16809984)         : double partial_ss[4096]                               32,768 B
//   [16842752)         : float patch_w[16]                                         64 B
//   [16842816)         : double loss_sum                                            8 B

// ---------------- K1: residuals + per-block variance partials ----------------
__global__ __launch_bounds__(256) void k_resid(
    const float4* __restrict__ out4, const float4* __restrict__ ema4,
    const float4* __restrict__ gt4, float4* __restrict__ rsr4,
    double* __restrict__ ps, double* __restrict__ pss)
{
    int t = blockIdx.x * 256 + threadIdx.x;   // float4-group index, 0..1048575
    int b = t >> 16;                          // 65536 groups per image
    int rem = t & 65535;
    int base = b * (CC * (HW / 4)) + rem;     // float4 units
    float4 rs = {0.f, 0.f, 0.f, 0.f};
    float4 re = {0.f, 0.f, 0.f, 0.f};
#pragma unroll
    for (int c = 0; c < CC; ++c) {
        float4 g = gt4[base + c * (HW / 4)];
        float4 o = out4[base + c * (HW / 4)];
        float4 e = ema4[base + c * (HW / 4)];
        rs.x += fabsf(g.x - o.x); rs.y += fabsf(g.y - o.y);
        rs.z += fabsf(g.z - o.z); rs.w += fabsf(g.w - o.w);
        re.x += fabsf(g.x - e.x); re.y += fabsf(g.y - e.y);
        re.z += fabsf(g.z - e.z); re.w += fabsf(g.w - e.w);
    }
    // encode mask (r_sr < r_ema) into sign bit (r_sr >= 0 always; -0.0 ok)
    float4 enc;
    enc.x = (rs.x < re.x) ? -rs.x : rs.x;
    enc.y = (rs.y < re.y) ? -rs.y : rs.y;
    enc.z = (rs.z < re.z) ? -rs.z : rs.z;
    enc.w = (rs.w < re.w) ? -rs.w : rs.w;
    rsr4[t] = enc;

    double s  = (double)rs.x + (double)rs.y + (double)rs.z + (double)rs.w;
    double ss = (double)rs.x * rs.x + (double)rs.y * rs.y +
                (double)rs.z * rs.z + (double)rs.w * rs.w;

    // wave reduce (64 lanes), then 4 wave partials via LDS
    for (int off = 32; off > 0; off >>= 1) {
        s  += __shfl_down(s, off);
        ss += __shfl_down(ss, off);
    }
    __shared__ double ws_s[4], ws_ss[4];
    int lane = threadIdx.x & 63, wid = threadIdx.x >> 6;
    if (lane == 0) { ws_s[wid] = s; ws_ss[wid] = ss; }
    __syncthreads();
    if (threadIdx.x == 0) {
        ps[blockIdx.x]  = ws_s[0] + ws_s[1] + ws_s[2] + ws_s[3];
        pss[blockIdx.x] = ws_ss[0] + ws_ss[1] + ws_ss[2] + ws_ss[3];
    }
}

// ---------------- K2: per-image variance -> patch weight; zero loss acc ------
__global__ __launch_bounds__(256) void k_patch(
    const double* __restrict__ ps, const double* __restrict__ pss,
    float* __restrict__ patch_w, double* __restrict__ loss_sum)
{
    int b = blockIdx.x;                   // 16 blocks
    int t = threadIdx.x;                  // 256 threads, one partial each
    double s  = ps[b * 256 + t];
    double ss = pss[b * 256 + t];
    for (int off = 32; off > 0; off >>= 1) {
        s  += __shfl_down(s, off);
        ss += __shfl_down(ss, off);
    }
    __shared__ double ws_s[4], ws_ss[4];
    int lane = t & 63, wid = t >> 6;
    if (lane == 0) { ws_s[wid] = s; ws_ss[wid] = ss; }
    __syncthreads();
    if (t == 0) {
        double S  = ws_s[0] + ws_s[1] + ws_s[2] + ws_s[3];
        double SS = ws_ss[0] + ws_ss[1] + ws_ss[2] + ws_ss[3];
        double n = (double)HW;
        double var = (SS - S * S / n) / (n - 1.0);
        patch_w[b] = powf((float)var, 0.2f);
        if (b == 0) *loss_sum = 0.0;
    }
}

// ---------------- K3: 7x7 local variance stencil + masked weighted loss ------
__global__ __launch_bounds__(256) void k_loss(
    const float* __restrict__ rsr, const float* __restrict__ patch_w,
    double* __restrict__ loss_sum)
{
    __shared__ float tile[38][38];        // 32x32 tile + 3 halo each side
    int b = blockIdx.z;
    int x0 = blockIdx.x * 32 - 3;
    int y0 = blockIdx.y * 32 - 3;
    const float* img = rsr + (size_t)b * HW;
    int t = threadIdx.y * 32 + threadIdx.x;

    for (int i = t; i < 38 * 38; i += 256) {
        int ly = i / 38, lx = i - ly * 38;
        int gy = y0 + ly;
        gy = gy < 0 ? -gy : (gy >= HH ? 2 * HH - 2 - gy : gy);
        int gx = x0 + lx;
        gx = gx < 0 ? -gx : (gx >= WW ? 2 * WW - 2 - gx : gx);
        tile[ly][lx] = img[gy * WW + gx];
    }
    __syncthreads();

    float pw = patch_w[b];
    double acc = 0.0;
#pragma unroll
    for (int j = 0; j < 4; ++j) {
        int py = threadIdx.y + 8 * j;     // output row within tile
        float s = 0.f, ss = 0.f;
#pragma unroll
        for (int dy = 0; dy < 7; ++dy)
#pragma unroll
            for (int dx = 0; dx < 7; ++dx) {
                float v = tile[py + dy][threadIdx.x + dx];
                float a = fabsf(v);       // decode (sign bit holds mask)
                s += a;
                ss += a * a;              // == v*v
            }
        float cen = tile[py + 3][threadIdx.x + 3];
        float r = fabsf(cen);
        float pvar = (ss - s * s / 49.0f) / 48.0f;  // unbiased 7x7 variance
        float wgt = pw * pvar;
        // mask: sign bit set => r_sr < r_ema => weight 0
        float contrib = (__float_as_uint(cen) >> 31) ? 0.0f : fabsf(wgt) * r;
        acc += (double)contrib;
    }

    for (int off = 32; off > 0; off >>= 1) acc += __shfl_down(acc, off);
    __shared__ double wsum[4];
    int lane = t & 63, wid = t >> 6;
    if (lane == 0) wsum[wid] = acc;
    __syncthreads();
    if (t == 0) atomicAdd(loss_sum, wsum[0] + wsum[1] + wsum[2] + wsum[3]);
}

// ---------------- K4: final mean ----------------
__global__ void k_final(const double* __restrict__ loss_sum, float* __restrict__ out)
{
    out[0] = (float)(*loss_sum / TOTAL);
}

extern "C" void kernel_launch(void* const* d_in, const int* in_sizes, int n_in,
                              void* d_out, int out_size, void* d_ws, size_t ws_size,
                              hipStream_t stream)
{
    const float4* out4 = (const float4*)d_in[0];
    const float4* ema4 = (const float4*)d_in[1];
    const float4* gt4  = (const float4*)d_in[2];

    char* ws = (char*)d_ws;
    float4* rsr4     = (float4*)(ws);
    float*  rsr      = (float*)(ws);
    double* ps       = (double*)(ws + 16777216);
    double* pss      = (double*)(ws + 16809984);
    float*  patch_w  = (float*)(ws + 16842752);
    double* loss_sum = (double*)(ws + 16842816);

    k_resid<<<4096, 256, 0, stream>>>(out4, ema4, gt4, rsr4, ps, pss);
    k_patch<<<16, 256, 0, stream>>>(ps, pss, patch_w, loss_sum);
    k_loss<<<dim3(16, 16, 16), dim3(32, 8), 0, stream>>>(rsr, patch_w, loss_sum);
    k_final<<<1, 1, 0, stream>>>(loss_sum, (float*)d_out);
}

// Round 2
// 202.130 us; speedup vs baseline: 1.1077x; 1.1077x over previous
//
#include <hip/hip_runtime.h>
#include <math.h>

#define BB 16
#define CC 3
#define HH 512
#define WW 512
#define HW (HH*WW)            // 262144
#define NPIX (BB*HW)          // 4194304
#define TOTAL ((double)(BB*CC*HW))  // 12582912

// ws layout (bytes):
//   [0)        : float rsr[NPIX]  (sign bit = mask r_sr < r_ema)   16,777,216 B
//   [16777216) : double ps[4096]                                       32,768 B
//   [16809984) : double pss[4096]                                      32,768 B
//   [16842752) : double loss_b[16]                                        128 B

// ---------------- K1: residuals + per-block variance partials ----------------
__global__ __launch_bounds__(256) void k_resid(
    const float4* __restrict__ out4, const float4* __restrict__ ema4,
    const float4* __restrict__ gt4, float4* __restrict__ rsr4,
    double* __restrict__ ps, double* __restrict__ pss,
    double* __restrict__ loss_b)
{
    int t = blockIdx.x * 256 + threadIdx.x;   // float4-group index, 0..1048575
    // zero the per-image loss accumulators (ws is poisoned each launch);
    // all of k_resid completes before k_loss starts (stream order).
    if (blockIdx.x < 16 && threadIdx.x == 0) loss_b[blockIdx.x] = 0.0;

    int b = t >> 16;                          // 65536 groups per image
    int rem = t & 65535;
    int base = b * (CC * (HW / 4)) + rem;     // float4 units
    float4 rs = {0.f, 0.f, 0.f, 0.f};
    float4 re = {0.f, 0.f, 0.f, 0.f};
#pragma unroll
    for (int c = 0; c < CC; ++c) {
        float4 g = gt4[base + c * (HW / 4)];
        float4 o = out4[base + c * (HW / 4)];
        float4 e = ema4[base + c * (HW / 4)];
        rs.x += fabsf(g.x - o.x); rs.y += fabsf(g.y - o.y);
        rs.z += fabsf(g.z - o.z); rs.w += fabsf(g.w - o.w);
        re.x += fabsf(g.x - e.x); re.y += fabsf(g.y - e.y);
        re.z += fabsf(g.z - e.z); re.w += fabsf(g.w - e.w);
    }
    // encode mask (r_sr < r_ema) into sign bit (r_sr >= 0 always; -0.0 ok)
    float4 enc;
    enc.x = (rs.x < re.x) ? -rs.x : rs.x;
    enc.y = (rs.y < re.y) ? -rs.y : rs.y;
    enc.z = (rs.z < re.z) ? -rs.z : rs.z;
    enc.w = (rs.w < re.w) ? -rs.w : rs.w;
    rsr4[t] = enc;

    double s  = (double)rs.x + (double)rs.y + (double)rs.z + (double)rs.w;
    double ss = (double)rs.x * rs.x + (double)rs.y * rs.y +
                (double)rs.z * rs.z + (double)rs.w * rs.w;

    for (int off = 32; off > 0; off >>= 1) {
        s  += __shfl_down(s, off);
        ss += __shfl_down(ss, off);
    }
    __shared__ double ws_s[4], ws_ss[4];
    int lane = threadIdx.x & 63, wid = threadIdx.x >> 6;
    if (lane == 0) { ws_s[wid] = s; ws_ss[wid] = ss; }
    __syncthreads();
    if (threadIdx.x == 0) {
        ps[blockIdx.x]  = ws_s[0] + ws_s[1] + ws_s[2] + ws_s[3];
        pss[blockIdx.x] = ws_ss[0] + ws_ss[1] + ws_ss[2] + ws_ss[3];
    }
}

// ---------------- K2: separable 7x7 local variance + masked partial loss -----
// 64x64 output tile, halo 3 -> 70x70 stage. Phase 1: horizontal sliding
// 7-window row sums (s, ss) into LDS float2. Phase 2: vertical sliding
// 7-window per thread. Per-image partial sums (without patch weight).
#define TS 64
#define TW 70          // TS + 6
#define TSTR 71        // padded tile stride (2-way max on strided reads)
#define RSTR 65        // padded float2 row stride

__global__ __launch_bounds__(256) void k_loss(
    const float* __restrict__ rsr, double* __restrict__ loss_b)
{
    __shared__ float tile[TW][TSTR];
    __shared__ float2 rs[TW][RSTR];

    int b = blockIdx.z;
    int x0 = blockIdx.x * TS - 3;
    int y0 = blockIdx.y * TS - 3;
    const float* img = rsr + (size_t)b * HW;
    int t = threadIdx.x;

    // ---- stage 70x70 (reflect-padded) ----
    for (int i = t; i < TW * TW; i += 256) {
        int ly = i / TW, lx = i - ly * TW;
        int gy = y0 + ly;
        gy = gy < 0 ? -gy : (gy >= HH ? 2 * HH - 2 - gy : gy);
        int gx = x0 + lx;
        gx = gx < 0 ? -gx : (gx >= WW ? 2 * WW - 2 - gx : gx);
        tile[ly][lx] = img[gy * WW + gx];
    }
    __syncthreads();

    // ---- phase 1: horizontal 7-window sums per row, sliding ----
    // tasks: (y in [0,70)) x (strip in [0,4)), strip covers 16 output cols
    for (int i = t; i < TW * 4; i += 256) {
        int y = i % TW;
        int st = i / TW;
        int xo0 = st * 16;
        float winS = 0.f, winSS = 0.f;
#pragma unroll
        for (int dx = 0; dx < 7; ++dx) {
            float v = tile[y][xo0 + dx];
            winS += fabsf(v);
            winSS = fmaf(v, v, winSS);
        }
        rs[y][xo0] = make_float2(winS, winSS);
#pragma unroll
        for (int k = 1; k < 16; ++k) {
            float vin  = tile[y][xo0 + k + 6];
            float vout = tile[y][xo0 + k - 1];
            winS += fabsf(vin) - fabsf(vout);
            winSS += fmaf(vin, vin, -(vout * vout));
            rs[y][xo0 + k] = make_float2(winS, winSS);
        }
    }
    __syncthreads();

    // ---- phase 2: vertical 7-window sliding per thread ----
    int x  = t & 63;           // output col
    int ys = t >> 6;           // 4 strips of 16 output rows
    int yo0 = ys * 16;
    float winS = 0.f, winSS = 0.f;
#pragma unroll
    for (int dy = 0; dy < 7; ++dy) {
        float2 v = rs[yo0 + dy][x];
        winS += v.x; winSS += v.y;
    }
    double acc = 0.0;
#pragma unroll
    for (int k = 0; k < 16; ++k) {
        int yo = yo0 + k;
        if (k) {
            float2 vin  = rs[yo + 6][x];
            float2 vout = rs[yo - 1][x];
            winS += vin.x - vout.x;
            winSS += vin.y - vout.y;
        }
        float cen = tile[yo + 3][x + 3];
        float r = fabsf(cen);
        float pvar = (winSS - winS * winS * (1.0f / 49.0f)) * (1.0f / 48.0f);
        // sign bit set => r_sr < r_ema => contributes 0
        float contrib = (__float_as_uint(cen) >> 31) ? 0.0f : fabsf(pvar) * r;
        acc += (double)contrib;
    }

    for (int off = 32; off > 0; off >>= 1) acc += __shfl_down(acc, off);
    __shared__ double wsum[4];
    int lane = t & 63, wid = t >> 6;
    if (lane == 0) wsum[wid] = acc;
    __syncthreads();
    if (t == 0) atomicAdd(&loss_b[b], wsum[0] + wsum[1] + wsum[2] + wsum[3]);
}

// ---------------- K3: per-image variance -> patch weight; final mean ---------
__global__ __launch_bounds__(256) void k_final(
    const double* __restrict__ ps, const double* __restrict__ pss,
    const double* __restrict__ loss_b, float* __restrict__ out)
{
    int t = threadIdx.x;
    __shared__ double sh_s[4], sh_ss[4];
    __shared__ double tot_sh;
    if (t == 0) tot_sh = 0.0;
    int lane = t & 63, wid = t >> 6;

    for (int b = 0; b < BB; ++b) {
        double s  = ps[b * 256 + t];
        double ss = pss[b * 256 + t];
        for (int off = 32; off > 0; off >>= 1) {
            s  += __shfl_down(s, off);
            ss += __shfl_down(ss, off);
        }
        if (lane == 0) { sh_s[wid] = s; sh_ss[wid] = ss; }
        __syncthreads();
        if (t == 0) {
            double S  = sh_s[0] + sh_s[1] + sh_s[2] + sh_s[3];
            double SS = sh_ss[0] + sh_ss[1] + sh_ss[2] + sh_ss[3];
            double n = (double)HW;
            double var = (SS - S * S / n) / (n - 1.0);
            float pw = powf((float)var, 0.2f);
            tot_sh += (double)pw * loss_b[b];
        }
        __syncthreads();
    }
    if (t == 0) out[0] = (float)(tot_sh / TOTAL);
}

extern "C" void kernel_launch(void* const* d_in, const int* in_sizes, int n_in,
                              void* d_out, int out_size, void* d_ws, size_t ws_size,
                              hipStream_t stream)
{
    const float4* out4 = (const float4*)d_in[0];
    const float4* ema4 = (const float4*)d_in[1];
    const float4* gt4  = (const float4*)d_in[2];

    char* ws = (char*)d_ws;
    float4* rsr4     = (float4*)(ws);
    float*  rsr      = (float*)(ws);
    double* ps       = (double*)(ws + 16777216);
    double* pss      = (double*)(ws + 16809984);
    double* loss_b   = (double*)(ws + 16842752);

    k_resid<<<4096, 256, 0, stream>>>(out4, ema4, gt4, rsr4, ps, pss, loss_b);
    k_loss<<<dim3(8, 8, BB), 256, 0, stream>>>(rsr, loss_b);
    k_final<<<1, 256, 0, stream>>>(ps, pss, loss_b, (float*)d_out);
}

// Round 3
// 176.177 us; speedup vs baseline: 1.2709x; 1.1473x over previous
//
#include <hip/hip_runtime.h>
#include <math.h>

#define BB 16
#define CC 3
#define HH 512
#define WW 512
#define HW (HH*WW)            // 262144
#define TOTAL ((double)(BB*CC*HW))  // 12582912

#define TSTR 76               // LDS tile row stride in floats (interior col base 4 -> 16B aligned)

// ws layout (bytes):
//   [0)     : double ps[1024]   per-block interior sum of r_sr
//   [8192)  : double pss[1024]  per-block interior sum of r_sr^2
//   [16384) : double pl[1024]   per-block loss partial (without patch weight)

// One block = one 64x64 output tile (grid 8x8x16).
// LDS tile holds encoded r_sr for the 70x70 halo region:
//   value = sum_c |gt-out|, sign bit set iff r_sr < r_ema (interior only; halo never a center).
__global__ __launch_bounds__(256, 5) void k_main(
    const float* __restrict__ outp, const float* __restrict__ emap,
    const float* __restrict__ gtp,
    double* __restrict__ ps, double* __restrict__ pss, double* __restrict__ pl)
{
    __shared__ float tile[70 * TSTR];
    __shared__ double red[12];

    const int t  = threadIdx.x;
    const int bx = blockIdx.x, by = blockIdx.y, b = blockIdx.z;
    const int x0 = bx * 64 - 3, y0 = by * 64 - 3;

    const size_t ib = (size_t)b * (CC * HW);
    const float4* o4 = (const float4*)(outp + ib);
    const float4* e4 = (const float4*)(emap + ib);
    const float4* g4 = (const float4*)(gtp + ib);

    double s_loc = 0.0, ss_loc = 0.0;

    // ---- Phase A: interior 64x64, float4-vectorized; ema read here only ----
    for (int iter = 0; iter < 4; ++iter) {
        int i   = iter * 256 + t;        // 0..1023
        int row = i >> 4;                // 0..63
        int fc  = i & 15;                // 0..15 (float4 col within tile)
        int idx = (by * 64 + row) * (WW / 4) + (bx * 16 + fc);
        float4 rs = {0.f, 0.f, 0.f, 0.f};
        float4 re = {0.f, 0.f, 0.f, 0.f};
#pragma unroll
        for (int c = 0; c < CC; ++c) {
            float4 g = g4[c * (HW / 4) + idx];
            float4 o = o4[c * (HW / 4) + idx];
            float4 e = e4[c * (HW / 4) + idx];
            rs.x += fabsf(g.x - o.x); rs.y += fabsf(g.y - o.y);
            rs.z += fabsf(g.z - o.z); rs.w += fabsf(g.w - o.w);
            re.x += fabsf(g.x - e.x); re.y += fabsf(g.y - e.y);
            re.z += fabsf(g.z - e.z); re.w += fabsf(g.w - e.w);
        }
        float4 enc;
        enc.x = (rs.x < re.x) ? -rs.x : rs.x;
        enc.y = (rs.y < re.y) ? -rs.y : rs.y;
        enc.z = (rs.z < re.z) ? -rs.z : rs.z;
        enc.w = (rs.w < re.w) ? -rs.w : rs.w;
        *(float4*)&tile[(row + 3) * TSTR + 4 + fc * 4] = enc;

        s_loc  += (double)rs.x + (double)rs.y + (double)rs.z + (double)rs.w;
        ss_loc += (double)rs.x * rs.x + (double)rs.y * rs.y +
                  (double)rs.z * rs.z + (double)rs.w * rs.w;
    }

    // ---- Phase B: halo ring (804 positions), scalar, reflect-mapped ----
    for (int i = t; i < 804; i += 256) {
        int ly, lx;
        if (i < 210)      { ly = i / 70;                lx = i % 70; }
        else if (i < 420) { int j = i - 210; ly = 67 + j / 70;  lx = j % 70; }
        else if (i < 612) { int j = i - 420; ly = 3 + (j & 63); lx = j >> 6; }
        else              { int j = i - 612; ly = 3 + (j & 63); lx = 67 + (j >> 6); }
        int gy = y0 + ly; gy = gy < 0 ? -gy : (gy >= HH ? 2 * HH - 2 - gy : gy);
        int gx = x0 + lx; gx = gx < 0 ? -gx : (gx >= WW ? 2 * WW - 2 - gx : gx);
        size_t idx = ib + (size_t)(gy * WW + gx);
        float r = 0.f;
#pragma unroll
        for (int c = 0; c < CC; ++c) {
            float g = gtp[idx + c * HW];
            float o = outp[idx + c * HW];
            r += fabsf(g - o);
        }
        tile[ly * TSTR + 1 + lx] = r;   // r >= +0, sign bit clear
    }
    __syncthreads();

    // ---- Phase C: separable 7x7 variance, row sums in a 7-deep register ring ----
    const int x  = t & 63;               // output col
    const int w  = t >> 6;               // strip: 16 output rows
    const int r0 = w * 16;

    float rS[7], rSS[7];
    float winS = 0.f, winSS = 0.f;
#pragma unroll
    for (int j = 0; j < 7; ++j) {
        float S = 0.f, SS = 0.f;
#pragma unroll
        for (int dx = 0; dx < 7; ++dx) {
            float v = tile[(r0 + j) * TSTR + x + 1 + dx];
            S += fabsf(v);
            SS = fmaf(v, v, SS);
        }
        rS[j] = S; rSS[j] = SS;
        winS += S; winSS += SS;
    }
    double acc = 0.0;
#pragma unroll
    for (int k = 0; k < 16; ++k) {
        if (k) {
            const int slot = (k - 1) % 7;          // compile-time (unrolled)
            float S = 0.f, SS = 0.f;
#pragma unroll
            for (int dx = 0; dx < 7; ++dx) {
                float v = tile[(r0 + k + 6) * TSTR + x + 1 + dx];
                S += fabsf(v);
                SS = fmaf(v, v, SS);
            }
            winS  += S  - rS[slot];
            winSS += SS - rSS[slot];
            rS[slot] = S; rSS[slot] = SS;
        }
        float cen = tile[(r0 + k + 3) * TSTR + x + 4];
        float rr  = fabsf(cen);
        float pvar = (winSS - winS * winS * (1.0f / 49.0f)) * (1.0f / 48.0f);
        float contrib = (__float_as_uint(cen) >> 31) ? 0.0f : fabsf(pvar) * rr;
        acc += (double)contrib;
    }

    // ---- block reduction -> per-block slots (no atomics, no init needed) ----
    for (int off = 32; off; off >>= 1) {
        s_loc  += __shfl_down(s_loc, off);
        ss_loc += __shfl_down(ss_loc, off);
        acc    += __shfl_down(acc, off);
    }
    if ((t & 63) == 0) { red[w] = s_loc; red[4 + w] = ss_loc; red[8 + w] = acc; }
    __syncthreads();
    if (t == 0) {
        int bid = b * 64 + by * 8 + bx;
        ps[bid]  = red[0] + red[1] + red[2] + red[3];
        pss[bid] = red[4] + red[5] + red[6] + red[7];
        pl[bid]  = red[8] + red[9] + red[10] + red[11];
    }
}

// ---- final: per-image variance -> patch weight, weighted total, mean ----
__global__ __launch_bounds__(256) void k_final(
    const double* __restrict__ ps, const double* __restrict__ pss,
    const double* __restrict__ pl, float* __restrict__ out)
{
    const int t = threadIdx.x, lane = t & 63, w = t >> 6;
    __shared__ double wacc[4];
    double tot = 0.0;
    for (int m = 0; m < 4; ++m) {
        int b = w * 4 + m;                 // each wave: 4 images
        double s  = ps[b * 64 + lane];
        double ss = pss[b * 64 + lane];
        double L  = pl[b * 64 + lane];
        for (int off = 32; off; off >>= 1) {
            s  += __shfl_down(s, off);
            ss += __shfl_down(ss, off);
            L  += __shfl_down(L, off);
        }
        if (lane == 0) {
            double n = (double)HW;
            double var = (ss - s * s / n) / (n - 1.0);
            tot += (double)powf((float)var, 0.2f) * L;
        }
    }
    if (lane == 0) wacc[w] = tot;
    __syncthreads();
    if (t == 0) out[0] = (float)((wacc[0] + wacc[1] + wacc[2] + wacc[3]) / TOTAL);
}

extern "C" void kernel_launch(void* const* d_in, const int* in_sizes, int n_in,
                              void* d_out, int out_size, void* d_ws, size_t ws_size,
                              hipStream_t stream)
{
    const float* outp = (const float*)d_in[0];
    const float* emap = (const float*)d_in[1];
    const float* gtp  = (const float*)d_in[2];

    char* ws = (char*)d_ws;
    double* ps  = (double*)(ws);
    double* pss = (double*)(ws + 8192);
    double* pl  = (double*)(ws + 16384);

    k_main<<<dim3(8, 8, BB), 256, 0, stream>>>(outp, emap, gtp, ps, pss, pl);
    k_final<<<1, 256, 0, stream>>>(ps, pss, pl, (float*)d_out);
}